// Round 8
// baseline (515.964 us; speedup 1.0000x reference)
//
#include <hip/hip_runtime.h>
#include <math.h>

#define NPTS 50000
#define NG   128
#define DD   32
#define FF   64
#define AA   8
#define HINC 1120   // DD + F + 2*F*A
#define EPSV 1e-5f
#define CH   64
#define SLOTS 10    // chunk slots per graph (last slot loops for overflow)

__device__ __forceinline__ float tanh_fast(float x) {
    float e = __expf(-2.f * fabsf(x));
    float r = __fdividef(1.f - e, 1.f + e);
    return copysignf(r, x);
}

// ---------------------------------------------------------------- setup: offs + stats zero + Weff/beff fold
__global__ __launch_bounds__(256) void k_setup(const int* __restrict__ batch,
                                               const float* __restrict__ W_in,
                                               const float* __restrict__ b_in,
                                               const float* __restrict__ W_out,
                                               const float* __restrict__ b_out,
                                               int* __restrict__ offs,
                                               float* __restrict__ stats,
                                               float* __restrict__ Weff,
                                               float* __restrict__ beff) {
    int t = threadIdx.x, bid = blockIdx.x;
    if (bid == 0) {
        if (t <= NG) {
            int lo = 0, hi = NPTS;
            while (lo < hi) { int mid = (lo+hi)>>1; if (batch[mid] < t) lo = mid+1; else hi = mid; }
            offs[t] = lo;
        }
        if (t < 32) stats[t] = 0.f;
    } else {
        int j = bid - 1;
        const float* W0 = W_out + (size_t)j*HINC*DD;   // rows 0..31
        const float* W1 = W0 + DD*DD;                  // rows 32..95
        const float* Wi = W_in + (size_t)j*DD*FF;
        for (int e = t; e < DD*DD; e += 256) {
            int i = e >> 5, d = e & 31;
            float s = W0[e];
            for (int f = 0; f < FF; f++) s += Wi[i*FF+f] * W1[f*DD+d];
            Weff[j*DD*DD + e] = s;
        }
        if (t < DD) {
            float s = b_out[j*DD + t];
            for (int f = 0; f < FF; f++) s += b_in[j*FF+f] * W1[f*DD+t];
            beff[j*DD + t] = s;
        }
    }
}

// ---------------------------------------------------------------- kA: (embed|gln) -> xp -> attn -> slot partials (sum,max)
__global__ __launch_bounds__(512) void k_A(const float* __restrict__ x,
                                           const float* __restrict__ Wi,
                                           const float* __restrict__ bi,
                                           const float* __restrict__ lniw,
                                           const float* __restrict__ lnib,
                                           const float* __restrict__ inb,
                                           const float* __restrict__ stats,
                                           const float* __restrict__ gw,
                                           const float* __restrict__ gb,
                                           const float* __restrict__ Win,
                                           const float* __restrict__ bin,
                                           const float* __restrict__ Wsc,
                                           const float* __restrict__ bsc,
                                           const int* __restrict__ offs,
                                           float* __restrict__ psum,
                                           float* __restrict__ pmax,
                                           float* __restrict__ hout,
                                           int isL0) {
    int g = blockIdx.x / SLOTS;
    int s = blockIdx.x - g*SLOTS;
    int gs = offs[g], cnt = offs[g+1] - gs;
    int start = s*CH;
    if (start >= cnt) return;                 // block-uniform early exit (no syncs yet)
    int end = (s == SLOTS-1) ? cnt : min(cnt, start + CH);

    __shared__ float sxp[CH][68];             // padded: conflict-free
    __shared__ float sattn[CH][9];
    __shared__ float sWin[DD*FF];
    __shared__ float sScT[AA*FF];             // Wsc transposed [a][f]

    const int t = threadIdx.x;
    ((float4*)sWin)[t] = ((const float4*)Win)[t];              // 512 float4 == 2048 floats
    { int a = t >> 6, f = t & 63; sScT[t] = Wsc[f*AA + a]; }   // 512 == AA*FF

    float gm = 0.f, ginv = 1.f;
    if (stats) {
        const float invM = 1.f/((float)NPTS*DD);
        gm = stats[0]*invM;
        float var = stats[1]*invM - gm*gm;
        ginv = 1.f/(sqrtf(fmaxf(var, 0.f)) + EPSV);
    }

    const int pt = t >> 3, q = t & 7;
    const int fo = q * 8, d4 = q * 4;
    const int ca = t >> 6, cf = t & 63;
    const float bscv = bsc[q];
    const float4 bi0 = *(const float4*)&bin[fo];
    const float4 bi1 = *(const float4*)&bin[fo+4];
    float csum = 0.f, cmax = -INFINITY;

    for (int base = gs + start; base < gs + end; base += CH) {
        int np = min(CH, gs + end - base);
        int n = base + pt;
        float hr4[4] = {0.f, 0.f, 0.f, 0.f};
        // ---- phase 1 (registers): embed for L0, gln-load otherwise
        if (pt < np) {
            if (isL0) {
                float x0 = x[n*3], x1 = x[n*3+1], x2 = x[n*3+2];
                float tv0 = x0*Wi[d4+0] + x1*Wi[DD+d4+0] + x2*Wi[2*DD+d4+0] + bi[d4+0];
                float tv1 = x0*Wi[d4+1] + x1*Wi[DD+d4+1] + x2*Wi[2*DD+d4+1] + bi[d4+1];
                float tv2 = x0*Wi[d4+2] + x1*Wi[DD+d4+2] + x2*Wi[2*DD+d4+2] + bi[d4+2];
                float tv3 = x0*Wi[d4+3] + x1*Wi[DD+d4+3] + x2*Wi[2*DD+d4+3] + bi[d4+3];
                float sm = (tv0+tv1) + (tv2+tv3);
                sm += __shfl_xor(sm, 1); sm += __shfl_xor(sm, 2); sm += __shfl_xor(sm, 4);
                float mm = sm * (1.f/DD);
                float c0 = tv0-mm, c1 = tv1-mm, c2 = tv2-mm, c3 = tv3-mm;
                float qq = (c0*c0 + c1*c1) + (c2*c2 + c3*c3);
                qq += __shfl_xor(qq, 1); qq += __shfl_xor(qq, 2); qq += __shfl_xor(qq, 4);
                float inv = 1.f/sqrtf(qq*(1.f/DD) + EPSV);
                hr4[0] = tanh_fast(c0*inv*lniw[d4+0] + lnib[d4+0]);
                hr4[1] = tanh_fast(c1*inv*lniw[d4+1] + lnib[d4+1]);
                hr4[2] = tanh_fast(c2*inv*lniw[d4+2] + lnib[d4+2]);
                hr4[3] = tanh_fast(c3*inv*lniw[d4+3] + lnib[d4+3]);
                *(float4*)&hout[(size_t)n*DD + d4] = make_float4(hr4[0],hr4[1],hr4[2],hr4[3]);
            } else {
                float4 v = *(const float4*)&inb[(size_t)n*DD + d4];
                float4 w4 = make_float4(1,1,1,1), b4 = make_float4(0,0,0,0);
                if (gw) { w4 = *(const float4*)&gw[d4]; b4 = *(const float4*)&gb[d4]; }
                hr4[0] = (v.x-gm)*ginv*w4.x + b4.x;
                hr4[1] = (v.y-gm)*ginv*w4.y + b4.y;
                hr4[2] = (v.z-gm)*ginv*w4.z + b4.z;
                hr4[3] = (v.w-gm)*ginv*w4.w + b4.w;
            }
        }
        __syncthreads();   // weights staged (iter 0) / sxp,sattn consumed (iter >0)
        // ---- phase 2: xp + attn (8 threads per point, h via intra-wave shuffle)
        if (pt < np) {
            float xr[8] = {bi0.x,bi0.y,bi0.z,bi0.w,bi1.x,bi1.y,bi1.z,bi1.w};
            #pragma unroll
            for (int k = 0; k < DD; k++) {
                float hv = __shfl(hr4[k & 3], (t & 56) | (k >> 2), 64);
                float4 wa = *(const float4*)&sWin[k*FF + fo];
                float4 wb = *(const float4*)&sWin[k*FF + fo + 4];
                xr[0] += hv*wa.x; xr[1] += hv*wa.y; xr[2] += hv*wa.z; xr[3] += hv*wa.w;
                xr[4] += hv*wb.x; xr[5] += hv*wb.y; xr[6] += hv*wb.z; xr[7] += hv*wb.w;
            }
            float pa[8];
            #pragma unroll
            for (int a = 0; a < 8; a++) {
                float4 wa = *(const float4*)&sScT[a*FF + fo];
                float4 wb = *(const float4*)&sScT[a*FF + fo + 4];
                pa[a] = xr[0]*wa.x + xr[1]*wa.y + xr[2]*wa.z + xr[3]*wa.w
                      + xr[4]*wb.x + xr[5]*wb.y + xr[6]*wb.z + xr[7]*wb.w;
            }
            #pragma unroll
            for (int msk = 1; msk < 8; msk <<= 1) {
                #pragma unroll
                for (int a = 0; a < 8; a++) pa[a] += __shfl_xor(pa[a], msk);
            }
            sattn[pt][q] = __expf(-fabsf(pa[q] + bscv));
            *(float4*)&sxp[pt][fo]   = make_float4(xr[0],xr[1],xr[2],xr[3]);
            *(float4*)&sxp[pt][fo+4] = make_float4(xr[4],xr[5],xr[6],xr[7]);
        }
        __syncthreads();
        // ---- phase 3: one (a,f) cell per thread
        #pragma unroll 4
        for (int pp = 0; pp < np; pp++) {
            float w = sattn[pp][ca] * sxp[pp][cf];
            csum += w; cmax = fmaxf(cmax, w);
        }
    }
    size_t pb = ((size_t)g*SLOTS + s)*512;
    psum[pb + t] = csum; pmax[pb + t] = cmax;
}

// ---------------------------------------------------------------- kB: reduce slot partials -> agg -> aggW = agg@Wagg + beff
__global__ __launch_bounds__(512) void k_B(const float* __restrict__ psum,
                                           const float* __restrict__ pmax,
                                           const int* __restrict__ offs,
                                           const float* __restrict__ Wagg,  // W_out[j] + 96*DD
                                           const float* __restrict__ beff,
                                           float* __restrict__ aggW) {
    int g = blockIdx.x, t = threadIdx.x;
    int cnt = offs[g+1] - offs[g];
    int nch = min((cnt + CH - 1)/CH, SLOTS);
    float sum = 0.f, mx = -INFINITY;
    size_t pb = (size_t)g*SLOTS*512;
    for (int s = 0; s < nch; s++) {
        sum += psum[pb + s*512 + t];
        mx = fmaxf(mx, pmax[pb + s*512 + t]);
    }
    float mean = sum / fmaxf((float)cnt, 1.f);
    if (cnt <= 0) { mean = 0.f; mx = 0.f; }
    __shared__ float agg[2*FF*AA];
    int a = t >> 6, f = t & 63;
    agg[a*2*FF + f]      = mean;
    agg[a*2*FF + FF + f] = mx;
    __syncthreads();
    int d = t & 31, grp = t >> 5;
    float acc = 0.f;
    #pragma unroll
    for (int k2 = 0; k2 < 64; k2++) {
        int k = grp*64 + k2;
        acc += agg[k] * Wagg[k*DD + d];
    }
    __shared__ float red[16][DD];
    red[grp][d] = acc;
    __syncthreads();
    if (t < DD) {
        float r = 0.f;
        #pragma unroll
        for (int qq = 0; qq < 16; qq++) r += red[qq][t];
        aggW[g*DD + t] = r + beff[t];
    }
}

// ---------------------------------------------------------------- kC: out = tanh(gln(in)@Weff + aggW[g]); global stats
__global__ __launch_bounds__(512) void k_C(const float* __restrict__ inb,
                                           const float* __restrict__ stats,
                                           const float* __restrict__ gw,
                                           const float* __restrict__ gb,
                                           const float* __restrict__ aggW,
                                           const int* __restrict__ batch,
                                           const float* __restrict__ Weff,
                                           float* __restrict__ tbuf,
                                           float* __restrict__ statsO) {
    __shared__ float sW[DD][36];
    __shared__ float rs1[8], rs2[8];
    const int t = threadIdx.x;
    for (int k = t; k < DD*DD; k += 512) sW[k>>5][k&31] = Weff[k];

    float gm = 0.f, ginv = 1.f;
    if (stats) {
        const float invM = 1.f/((float)NPTS*DD);
        gm = stats[0]*invM;
        float var = stats[1]*invM - gm*gm;
        ginv = 1.f/(sqrtf(fmaxf(var, 0.f)) + EPSV);
    }
    const int b0 = blockIdx.x * CH;
    const int np = min(CH, NPTS - b0);
    const int pt = t >> 3, q = t & 7, d4 = q * 4;
    const int n = b0 + pt;
    float hr4[4] = {0.f, 0.f, 0.f, 0.f};
    if (pt < np) {
        float4 v = *(const float4*)&inb[(size_t)n*DD + d4];
        float4 w4 = make_float4(1,1,1,1), b4 = make_float4(0,0,0,0);
        if (gw) { w4 = *(const float4*)&gw[d4]; b4 = *(const float4*)&gb[d4]; }
        hr4[0] = (v.x-gm)*ginv*w4.x + b4.x;
        hr4[1] = (v.y-gm)*ginv*w4.y + b4.y;
        hr4[2] = (v.z-gm)*ginv*w4.z + b4.z;
        hr4[3] = (v.w-gm)*ginv*w4.w + b4.w;
    }
    __syncthreads();   // sW ready
    float s1 = 0.f, s2 = 0.f;
    if (pt < np) {
        int g = batch[n];
        float4 a0 = *(const float4*)&aggW[g*DD + d4];
        float acc0 = a0.x, acc1 = a0.y, acc2 = a0.z, acc3 = a0.w;
        #pragma unroll
        for (int k = 0; k < DD; k++) {
            float hv = __shfl(hr4[k & 3], (t & 56) | (k >> 2), 64);
            float4 w = *(const float4*)&sW[k][d4];
            acc0 += hv*w.x; acc1 += hv*w.y; acc2 += hv*w.z; acc3 += hv*w.w;
        }
        float4 o;
        o.x = tanh_fast(acc0); o.y = tanh_fast(acc1);
        o.z = tanh_fast(acc2); o.w = tanh_fast(acc3);
        *(float4*)&tbuf[(size_t)n*DD + d4] = o;
        s1 = (o.x + o.y) + (o.z + o.w);
        s2 = (o.x*o.x + o.y*o.y) + (o.z*o.z + o.w*o.w);
    }
    #pragma unroll
    for (int o = 32; o > 0; o >>= 1) { s1 += __shfl_down(s1, o); s2 += __shfl_down(s2, o); }
    int wid = t >> 6;
    if ((t & 63) == 0) { rs1[wid] = s1; rs2[wid] = s2; }
    __syncthreads();
    if (t == 0) {
        float a1 = 0.f, a2 = 0.f;
        #pragma unroll
        for (int qq = 0; qq < 8; qq++) { a1 += rs1[qq]; a2 += rs2[qq]; }
        atomicAdd(&statsO[0], a1);
        atomicAdd(&statsO[1], a2);
    }
}

// ---------------------------------------------------------------- readout: segment mean of gln(tbuf) -> 3x (dense+ln+tanh) -> dot
__global__ __launch_bounds__(256) void k_read(const float* __restrict__ tbuf,
                                              const float* __restrict__ stats,
                                              const float* __restrict__ gw,
                                              const float* __restrict__ gb,
                                              const int* __restrict__ offs,
                                              const float* __restrict__ Wp,
                                              const float* __restrict__ bp,
                                              const float* __restrict__ lnw,
                                              const float* __restrict__ lnb,
                                              const float* __restrict__ Wpo,
                                              const float* __restrict__ bpo,
                                              float* __restrict__ out) {
    int g = blockIdx.x;
    int t = threadIdx.x;
    int d = t & 31, pl = t >> 5;   // 8 point-lanes x 32 dims
    int s0 = offs[g], e0 = offs[g+1];
    float acc = 0.f;
    for (int n = s0 + pl; n < e0; n += 8) acc += tbuf[(size_t)n*DD + d];
    __shared__ float red[8][DD];
    red[pl][d] = acc;
    __syncthreads();
    __shared__ float sv[DD];
    if (t < DD) {
        float r = 0.f;
        #pragma unroll
        for (int qq = 0; qq < 8; qq++) r += red[qq][t];
        const float invM = 1.f/((float)NPTS*DD);
        float m = stats[0]*invM;
        float var = stats[1]*invM - m*m;
        float inv = 1.f/(sqrtf(fmaxf(var, 0.f)) + EPSV);
        float cnt = (float)(e0 - s0);
        float mean = r / fmaxf(cnt, 1.f);
        sv[t] = (e0 > s0) ? (mean - m)*inv*gw[t] + gb[t] : 0.f;
    }
    __syncthreads();
    for (int j = 0; j < 3; j++) {
        float yv = 0.f;
        if (t < DD) {
            float y = bp[j*DD + t];
            #pragma unroll
            for (int i = 0; i < DD; i++) y += sv[i] * Wp[j*DD*DD + i*DD + t];
            float sum = y;
            #pragma unroll
            for (int o = 1; o < 32; o <<= 1) sum += __shfl_xor(sum, o);
            float m = sum * (1.f/DD);
            float c = y - m;
            float sq = c*c;
            #pragma unroll
            for (int o = 1; o < 32; o <<= 1) sq += __shfl_xor(sq, o);
            float var = sq * (1.f/DD);
            yv = tanh_fast(c / sqrtf(var + EPSV) * lnw[j*DD+t] + lnb[j*DD+t]);
        }
        __syncthreads();
        if (t < DD) sv[t] = yv;
        __syncthreads();
    }
    if (t < DD) {
        float p = sv[t] * Wpo[t];
        #pragma unroll
        for (int o = 1; o < 32; o <<= 1) p += __shfl_xor(p, o);
        if (t == 0) out[g] = p + bpo[0];
    }
}

extern "C" void kernel_launch(void* const* d_in, const int* in_sizes, int n_in,
                              void* d_out, int out_size, void* d_ws, size_t ws_size,
                              hipStream_t stream) {
    const float* x     = (const float*)d_in[0];
    const int*   batch = (const int*)  d_in[1];
    const float* Wi    = (const float*)d_in[2];
    const float* bi    = (const float*)d_in[3];
    const float* lni_w = (const float*)d_in[4];
    const float* lni_b = (const float*)d_in[5];
    const float* W_in  = (const float*)d_in[6];
    const float* b_in  = (const float*)d_in[7];
    const float* W_sc  = (const float*)d_in[8];
    const float* b_sc  = (const float*)d_in[9];
    const float* W_out = (const float*)d_in[10];
    const float* b_out = (const float*)d_in[11];
    const float* gln_w = (const float*)d_in[12];
    const float* gln_b = (const float*)d_in[13];
    const float* Wp    = (const float*)d_in[14];
    const float* bp    = (const float*)d_in[15];
    const float* lnp_w = (const float*)d_in[16];
    const float* lnp_b = (const float*)d_in[17];
    const float* Wpo   = (const float*)d_in[18];
    const float* bpo   = (const float*)d_in[19];
    float* out = (float*)d_out;

    float* ws    = (float*)d_ws;
    float* h     = ws;                                  // NPTS*32
    float* tbuf  = h + (size_t)NPTS*DD;                 // NPTS*32
    float* aggW  = tbuf + (size_t)NPTS*DD;              // NG*32
    float* stats = aggW + NG*DD;                        // 32
    float* Weff  = stats + 32;                          // 3*1024
    float* beff  = Weff + 3*DD*DD;                      // 96
    float* psum  = beff + 3*DD;                         // NG*SLOTS*512
    float* pmax  = psum + (size_t)NG*SLOTS*512;         // NG*SLOTS*512
    int*   offs  = (int*)(pmax + (size_t)NG*SLOTS*512); // NG+1

    k_setup<<<4, 256, 0, stream>>>(batch, W_in, b_in, W_out, b_out, offs, stats, Weff, beff);

    for (int L = 0; L < 9; ++L) {
        int j = L % 3;
        int pj = (L + 2) % 3;
        const float* inb = L ? tbuf : h;
        const float* st  = L ? stats + 2*(L-1) : nullptr;
        const float* pgw = L ? gln_w + pj*DD : nullptr;
        const float* pgb = L ? gln_b + pj*DD : nullptr;
        k_A<<<NG*SLOTS, 512, 0, stream>>>(
            x, Wi, bi, lni_w, lni_b,
            inb, st, pgw, pgb,
            W_in + (size_t)j*DD*FF, b_in + j*FF,
            W_sc + (size_t)j*FF*AA, b_sc + j*AA,
            offs, psum, pmax, h, (L == 0) ? 1 : 0);
        k_B<<<NG, 512, 0, stream>>>(
            psum, pmax, offs,
            W_out + (size_t)j*HINC*DD + (size_t)96*DD, beff + j*DD, aggW);
        k_C<<<(NPTS+CH-1)/CH, 512, 0, stream>>>(
            inb, st, pgw, pgb, aggW, batch,
            Weff + (size_t)j*DD*DD, tbuf, stats + 2*L);
    }
    k_read<<<NG, 256, 0, stream>>>(tbuf, stats + 16, gln_w + 2*DD, gln_b + 2*DD,
                                   offs, Wp, bp, lnp_w, lnp_b, Wpo, bpo, out);
}

// Round 9
// 450.114 us; speedup vs baseline: 1.1463x; 1.1463x over previous
//
#include <hip/hip_runtime.h>
#include <math.h>

#define NPTS 50000
#define NG   128
#define DD   32
#define FF   64
#define AA   8
#define HINC 1120   // DD + FF + 2*FF*AA
#define EPSV 1e-5f
#define CH   64
#define SLOTS 10    // chunk slots per graph (last slot loops for overflow)

__device__ __forceinline__ float tanh_fast(float x) {
    float e = __expf(-2.f * fabsf(x));
    float r = __fdividef(1.f - e, 1.f + e);
    return copysignf(r, x);
}

// ---------------------------------------------------------------- setup: offs + stats zero + Weff/beff fold
__global__ __launch_bounds__(256) void k_setup(const int* __restrict__ batch,
                                               const float* __restrict__ W_in,
                                               const float* __restrict__ b_in,
                                               const float* __restrict__ W_out,
                                               const float* __restrict__ b_out,
                                               int* __restrict__ offs,
                                               float* __restrict__ stats,
                                               float* __restrict__ Weff,
                                               float* __restrict__ beff) {
    int t = threadIdx.x, bid = blockIdx.x;
    if (bid == 0) {
        if (t <= NG) {
            int lo = 0, hi = NPTS;
            while (lo < hi) { int mid = (lo+hi)>>1; if (batch[mid] < t) lo = mid+1; else hi = mid; }
            offs[t] = lo;
        }
        if (t < 32) stats[t] = 0.f;
    } else {
        int j = bid - 1;
        const float* W0 = W_out + (size_t)j*HINC*DD;   // rows 0..31
        const float* W1 = W0 + DD*DD;                  // rows 32..95
        const float* Wi = W_in + (size_t)j*DD*FF;
        for (int e = t; e < DD*DD; e += 256) {
            int i = e >> 5, d = e & 31;
            float s = W0[e];
            for (int f = 0; f < FF; f++) s += Wi[i*FF+f] * W1[f*DD+d];
            Weff[j*DD*DD + e] = s;
        }
        if (t < DD) {
            float s = b_out[j*DD + t];
            for (int f = 0; f < FF; f++) s += b_in[j*FF+f] * W1[f*DD+t];
            beff[j*DD + t] = s;
        }
    }
}

// ---------------------------------------------------------------- kA: (embed|gln) -> xp -> attn -> slot partials (sum,max)
// r3-proven structure: hs LDS staging; embed fused for L0 (r6-verified)
__global__ __launch_bounds__(512) void k_A(const float* __restrict__ x,
                                           const float* __restrict__ Wi,
                                           const float* __restrict__ bi,
                                           const float* __restrict__ lniw,
                                           const float* __restrict__ lnib,
                                           const float* __restrict__ inb,
                                           const float* __restrict__ stats,
                                           const float* __restrict__ gw,
                                           const float* __restrict__ gb,
                                           const float* __restrict__ Win,
                                           const float* __restrict__ bin,
                                           const float* __restrict__ Wsc,
                                           const float* __restrict__ bsc,
                                           const int* __restrict__ offs,
                                           float* __restrict__ psum,
                                           float* __restrict__ pmax,
                                           float* __restrict__ hout,
                                           int isL0) {
    int g = blockIdx.x / SLOTS;
    int s = blockIdx.x - g*SLOTS;
    int gs = offs[g], cnt = offs[g+1] - gs;
    int start = s*CH;
    if (start >= cnt) return;                 // block-uniform early exit (no syncs yet)
    int end = (s == SLOTS-1) ? cnt : min(cnt, start + CH);

    __shared__ float hs[CH][36];
    __shared__ float sxp[CH][68];             // padded: conflict-free
    __shared__ float sattn[CH][9];
    __shared__ float sWin[DD*FF];
    __shared__ float sScT[AA*FF];             // Wsc transposed [a][f]

    const int t = threadIdx.x;
    ((float4*)sWin)[t] = ((const float4*)Win)[t];              // 512 float4 == 2048 floats
    { int a = t >> 6, f = t & 63; sScT[t] = Wsc[f*AA + a]; }   // 512 == AA*FF

    float gm = 0.f, ginv = 1.f;
    if (stats) {
        const float invM = 1.f/((float)NPTS*DD);
        gm = stats[0]*invM;
        float var = stats[1]*invM - gm*gm;
        ginv = 1.f/(sqrtf(fmaxf(var, 0.f)) + EPSV);
    }

    const int pt = t >> 3, q = t & 7;
    const int fo = q * 8;
    const int ca = t >> 6, cf = t & 63;
    const float bscv = bsc[q];
    const float4 bi0 = *(const float4*)&bin[fo];
    const float4 bi1 = *(const float4*)&bin[fo+4];
    float csum = 0.f, cmax = -INFINITY;

    for (int base = gs + start; base < gs + end; base += CH) {
        int np = min(CH, gs + end - base);
        __syncthreads();                      // weights staged (iter 0) / LDS consumed (iter >0)
        // ---- phase 1: stage point rows into hs (embed for L0, gln-load otherwise)
        {
            int pp = t >> 3, d4 = (t & 7)*4;
            if (pp < np) {
                int n = base + pp;
                if (isL0) {
                    float x0 = x[n*3], x1 = x[n*3+1], x2 = x[n*3+2];
                    float tv0 = x0*Wi[d4+0] + x1*Wi[DD+d4+0] + x2*Wi[2*DD+d4+0] + bi[d4+0];
                    float tv1 = x0*Wi[d4+1] + x1*Wi[DD+d4+1] + x2*Wi[2*DD+d4+1] + bi[d4+1];
                    float tv2 = x0*Wi[d4+2] + x1*Wi[DD+d4+2] + x2*Wi[2*DD+d4+2] + bi[d4+2];
                    float tv3 = x0*Wi[d4+3] + x1*Wi[DD+d4+3] + x2*Wi[2*DD+d4+3] + bi[d4+3];
                    float sm = (tv0+tv1) + (tv2+tv3);
                    sm += __shfl_xor(sm, 1); sm += __shfl_xor(sm, 2); sm += __shfl_xor(sm, 4);
                    float mm = sm * (1.f/DD);
                    float c0 = tv0-mm, c1 = tv1-mm, c2 = tv2-mm, c3 = tv3-mm;
                    float qq = (c0*c0 + c1*c1) + (c2*c2 + c3*c3);
                    qq += __shfl_xor(qq, 1); qq += __shfl_xor(qq, 2); qq += __shfl_xor(qq, 4);
                    float inv = 1.f/sqrtf(qq*(1.f/DD) + EPSV);
                    float o0 = tanh_fast(c0*inv*lniw[d4+0] + lnib[d4+0]);
                    float o1 = tanh_fast(c1*inv*lniw[d4+1] + lnib[d4+1]);
                    float o2 = tanh_fast(c2*inv*lniw[d4+2] + lnib[d4+2]);
                    float o3 = tanh_fast(c3*inv*lniw[d4+3] + lnib[d4+3]);
                    hs[pp][d4+0] = o0; hs[pp][d4+1] = o1; hs[pp][d4+2] = o2; hs[pp][d4+3] = o3;
                    *(float4*)&hout[(size_t)n*DD + d4] = make_float4(o0,o1,o2,o3);
                } else {
                    float4 v = *(const float4*)&inb[(size_t)n*DD + d4];
                    float4 w4 = make_float4(1,1,1,1), b4 = make_float4(0,0,0,0);
                    if (gw) { w4 = *(const float4*)&gw[d4]; b4 = *(const float4*)&gb[d4]; }
                    hs[pp][d4+0] = (v.x-gm)*ginv*w4.x + b4.x;
                    hs[pp][d4+1] = (v.y-gm)*ginv*w4.y + b4.y;
                    hs[pp][d4+2] = (v.z-gm)*ginv*w4.z + b4.z;
                    hs[pp][d4+3] = (v.w-gm)*ginv*w4.w + b4.w;
                }
            }
        }
        __syncthreads();
        // ---- phase 2: xp + attn (8 threads per point)
        if (pt < np) {
            float xr[8] = {bi0.x,bi0.y,bi0.z,bi0.w,bi1.x,bi1.y,bi1.z,bi1.w};
            #pragma unroll
            for (int k = 0; k < DD; k++) {
                float hv = hs[pt][k];
                float4 wa = *(const float4*)&sWin[k*FF + fo];
                float4 wb = *(const float4*)&sWin[k*FF + fo + 4];
                xr[0] += hv*wa.x; xr[1] += hv*wa.y; xr[2] += hv*wa.z; xr[3] += hv*wa.w;
                xr[4] += hv*wb.x; xr[5] += hv*wb.y; xr[6] += hv*wb.z; xr[7] += hv*wb.w;
            }
            float pa[8];
            #pragma unroll
            for (int a = 0; a < 8; a++) {
                float4 wa = *(const float4*)&sScT[a*FF + fo];
                float4 wb = *(const float4*)&sScT[a*FF + fo + 4];
                pa[a] = xr[0]*wa.x + xr[1]*wa.y + xr[2]*wa.z + xr[3]*wa.w
                      + xr[4]*wb.x + xr[5]*wb.y + xr[6]*wb.z + xr[7]*wb.w;
            }
            #pragma unroll
            for (int msk = 1; msk < 8; msk <<= 1) {
                #pragma unroll
                for (int a = 0; a < 8; a++) pa[a] += __shfl_xor(pa[a], msk);
            }
            sattn[pt][q] = __expf(-fabsf(pa[q] + bscv));
            *(float4*)&sxp[pt][fo]   = make_float4(xr[0],xr[1],xr[2],xr[3]);
            *(float4*)&sxp[pt][fo+4] = make_float4(xr[4],xr[5],xr[6],xr[7]);
        }
        __syncthreads();
        // ---- phase 3: accumulate one (a,f) cell per thread
        for (int pp = 0; pp < np; pp++) {
            float w = sattn[pp][ca] * sxp[pp][cf];
            csum += w; cmax = fmaxf(cmax, w);
        }
    }
    size_t pb = ((size_t)g*SLOTS + s)*512;
    psum[pb + t] = csum; pmax[pb + t] = cmax;
}

// ---------------------------------------------------------------- kB: reduce slot partials -> agg -> aggW = agg@Wagg + beff
__global__ __launch_bounds__(512) void k_B(const float* __restrict__ psum,
                                           const float* __restrict__ pmax,
                                           const int* __restrict__ offs,
                                           const float* __restrict__ Wagg,  // W_out[j] + 96*DD
                                           const float* __restrict__ beff,
                                           float* __restrict__ aggW) {
    int g = blockIdx.x, t = threadIdx.x;
    int cnt = offs[g+1] - offs[g];
    int nch = min((cnt + CH - 1)/CH, SLOTS);
    float sum = 0.f, mx = -INFINITY;
    size_t pb = (size_t)g*SLOTS*512;
    for (int s = 0; s < nch; s++) {
        sum += psum[pb + s*512 + t];
        mx = fmaxf(mx, pmax[pb + s*512 + t]);
    }
    float mean = sum / fmaxf((float)cnt, 1.f);
    if (cnt <= 0) { mean = 0.f; mx = 0.f; }
    __shared__ float agg[2*FF*AA];
    int a = t >> 6, f = t & 63;
    agg[a*2*FF + f]      = mean;
    agg[a*2*FF + FF + f] = mx;
    __syncthreads();
    int d = t & 31, grp = t >> 5;    // 16 groups x 64 k
    float acc = 0.f;
    #pragma unroll
    for (int k2 = 0; k2 < 64; k2++) {
        int k = grp*64 + k2;
        acc += agg[k] * Wagg[k*DD + d];
    }
    __shared__ float red[16][DD];
    red[grp][d] = acc;
    __syncthreads();
    if (t < DD) {
        float r = 0.f;
        #pragma unroll
        for (int qq = 0; qq < 16; qq++) r += red[qq][t];
        aggW[g*DD + t] = r + beff[t];
    }
}

// ---------------------------------------------------------------- kC: out = tanh(gln(in)@Weff + aggW[g]); global stats (r3-proven)
__global__ __launch_bounds__(512) void k_C(const float* __restrict__ inb,
                                           const float* __restrict__ stats,
                                           const float* __restrict__ gw,
                                           const float* __restrict__ gb,
                                           const float* __restrict__ aggW,
                                           const int* __restrict__ batch,
                                           const float* __restrict__ Weff,
                                           float* __restrict__ tbuf,
                                           float* __restrict__ statsO) {
    __shared__ float hs[64][36];
    __shared__ float sW[DD][36];
    int t = threadIdx.x;
    for (int k = t; k < DD*DD; k += 512) sW[k >> 5][k & 31] = Weff[k];

    float m = 0.f, inv = 1.f;
    if (stats) {
        const float invM = 1.f/((float)NPTS*DD);
        m = stats[0]*invM;
        float var = stats[1]*invM - m*m;
        inv = 1.f/(sqrtf(fmaxf(var, 0.f)) + EPSV);
    }
    int b0 = blockIdx.x * 64;
    // phase 1: load + gln
    {
        int pp = t >> 3, d4 = (t & 7)*4;
        int n = b0 + pp;
        if (n < NPTS) {
            float4 v = *(const float4*)&inb[(size_t)n*DD + d4];
            float4 w4 = make_float4(1,1,1,1), b4 = make_float4(0,0,0,0);
            if (gw) { w4 = *(const float4*)&gw[d4]; b4 = *(const float4*)&gb[d4]; }
            hs[pp][d4+0] = (v.x-m)*inv*w4.x + b4.x;
            hs[pp][d4+1] = (v.y-m)*inv*w4.y + b4.y;
            hs[pp][d4+2] = (v.z-m)*inv*w4.z + b4.z;
            hs[pp][d4+3] = (v.w-m)*inv*w4.w + b4.w;
        }
    }
    __syncthreads();
    int pt = t >> 3, q4 = (t & 7)*4;
    int n = b0 + pt;
    float s1 = 0.f, s2 = 0.f;
    if (n < NPTS) {
        int g = batch[n];
        float4 a0 = *(const float4*)&aggW[g*DD + q4];
        float acc0 = a0.x, acc1 = a0.y, acc2 = a0.z, acc3 = a0.w;
        #pragma unroll
        for (int k = 0; k < DD; k++) {
            float hv = hs[pt][k];
            float4 w = *(const float4*)&sW[k][q4];
            acc0 += hv*w.x; acc1 += hv*w.y; acc2 += hv*w.z; acc3 += hv*w.w;
        }
        float4 o;
        o.x = tanh_fast(acc0); o.y = tanh_fast(acc1);
        o.z = tanh_fast(acc2); o.w = tanh_fast(acc3);
        *(float4*)&tbuf[(size_t)n*DD + q4] = o;
        s1 = (o.x + o.y) + (o.z + o.w);
        s2 = (o.x*o.x + o.y*o.y) + (o.z*o.z + o.w*o.w);
    }
    #pragma unroll
    for (int o = 32; o > 0; o >>= 1) { s1 += __shfl_down(s1, o); s2 += __shfl_down(s2, o); }
    __shared__ float rs1[8], rs2[8];
    int wid = t >> 6;
    if ((t & 63) == 0) { rs1[wid] = s1; rs2[wid] = s2; }
    __syncthreads();
    if (t == 0) {
        float a1 = 0.f, a2 = 0.f;
        #pragma unroll
        for (int qq = 0; qq < 8; qq++) { a1 += rs1[qq]; a2 += rs2[qq]; }
        atomicAdd(&statsO[0], a1);
        atomicAdd(&statsO[1], a2);
    }
}

// ---------------------------------------------------------------- readout: segment mean of gln(tbuf) -> 3x (dense+ln+tanh) -> dot
__global__ __launch_bounds__(256) void k_read(const float* __restrict__ tbuf,
                                              const float* __restrict__ stats,
                                              const float* __restrict__ gw,
                                              const float* __restrict__ gb,
                                              const int* __restrict__ offs,
                                              const float* __restrict__ Wp,
                                              const float* __restrict__ bp,
                                              const float* __restrict__ lnw,
                                              const float* __restrict__ lnb,
                                              const float* __restrict__ Wpo,
                                              const float* __restrict__ bpo,
                                              float* __restrict__ out) {
    int g = blockIdx.x;
    int t = threadIdx.x;
    int d = t & 31, pl = t >> 5;   // 8 point-lanes x 32 dims
    int s0 = offs[g], e0 = offs[g+1];
    float acc = 0.f;
    for (int n = s0 + pl; n < e0; n += 8) acc += tbuf[(size_t)n*DD + d];
    __shared__ float red[8][DD];
    red[pl][d] = acc;
    __syncthreads();
    __shared__ float sv[DD];
    if (t < DD) {
        float r = 0.f;
        #pragma unroll
        for (int qq = 0; qq < 8; qq++) r += red[qq][t];
        const float invM = 1.f/((float)NPTS*DD);
        float m = stats[0]*invM;
        float var = stats[1]*invM - m*m;
        float inv = 1.f/(sqrtf(fmaxf(var, 0.f)) + EPSV);
        float cnt = (float)(e0 - s0);
        float mean = r / fmaxf(cnt, 1.f);
        sv[t] = (e0 > s0) ? (mean - m)*inv*gw[t] + gb[t] : 0.f;
    }
    __syncthreads();
    for (int j = 0; j < 3; j++) {
        float yv = 0.f;
        if (t < DD) {
            float y = bp[j*DD + t];
            #pragma unroll
            for (int i = 0; i < DD; i++) y += sv[i] * Wp[j*DD*DD + i*DD + t];
            float sum = y;
            #pragma unroll
            for (int o = 1; o < 32; o <<= 1) sum += __shfl_xor(sum, o);
            float m = sum * (1.f/DD);
            float c = y - m;
            float sq = c*c;
            #pragma unroll
            for (int o = 1; o < 32; o <<= 1) sq += __shfl_xor(sq, o);
            float var = sq * (1.f/DD);
            yv = tanh_fast(c / sqrtf(var + EPSV) * lnw[j*DD+t] + lnb[j*DD+t]);
        }
        __syncthreads();
        if (t < DD) sv[t] = yv;
        __syncthreads();
    }
    if (t < DD) {
        float p = sv[t] * Wpo[t];
        #pragma unroll
        for (int o = 1; o < 32; o <<= 1) p += __shfl_xor(p, o);
        if (t == 0) out[g] = p + bpo[0];
    }
}

extern "C" void kernel_launch(void* const* d_in, const int* in_sizes, int n_in,
                              void* d_out, int out_size, void* d_ws, size_t ws_size,
                              hipStream_t stream) {
    const float* x     = (const float*)d_in[0];
    const int*   batch = (const int*)  d_in[1];
    const float* Wi    = (const float*)d_in[2];
    const float* bi    = (const float*)d_in[3];
    const float* lni_w = (const float*)d_in[4];
    const float* lni_b = (const float*)d_in[5];
    const float* W_in  = (const float*)d_in[6];
    const float* b_in  = (const float*)d_in[7];
    const float* W_sc  = (const float*)d_in[8];
    const float* b_sc  = (const float*)d_in[9];
    const float* W_out = (const float*)d_in[10];
    const float* b_out = (const float*)d_in[11];
    const float* gln_w = (const float*)d_in[12];
    const float* gln_b = (const float*)d_in[13];
    const float* Wp    = (const float*)d_in[14];
    const float* bp    = (const float*)d_in[15];
    const float* lnp_w = (const float*)d_in[16];
    const float* lnp_b = (const float*)d_in[17];
    const float* Wpo   = (const float*)d_in[18];
    const float* bpo   = (const float*)d_in[19];
    float* out = (float*)d_out;

    float* ws    = (float*)d_ws;
    float* h     = ws;                                  // NPTS*32
    float* tbuf  = h + (size_t)NPTS*DD;                 // NPTS*32
    float* aggW  = tbuf + (size_t)NPTS*DD;              // NG*32
    float* stats = aggW + NG*DD;                        // 32
    float* Weff  = stats + 32;                          // 3*1024
    float* beff  = Weff + 3*DD*DD;                      // 96
    float* psum  = beff + 3*DD;                         // NG*SLOTS*512
    float* pmax  = psum + (size_t)NG*SLOTS*512;         // NG*SLOTS*512
    int*   offs  = (int*)(pmax + (size_t)NG*SLOTS*512); // NG+1

    k_setup<<<4, 256, 0, stream>>>(batch, W_in, b_in, W_out, b_out, offs, stats, Weff, beff);

    for (int L = 0; L < 9; ++L) {
        int j = L % 3;
        int pj = (L + 2) % 3;
        const float* inb = L ? tbuf : h;
        const float* st  = L ? stats + 2*(L-1) : nullptr;
        const float* pgw = L ? gln_w + pj*DD : nullptr;
        const float* pgb = L ? gln_b + pj*DD : nullptr;
        k_A<<<NG*SLOTS, 512, 0, stream>>>(
            x, Wi, bi, lni_w, lni_b,
            inb, st, pgw, pgb,
            W_in + (size_t)j*DD*FF, b_in + j*FF,
            W_sc + (size_t)j*FF*AA, b_sc + j*AA,
            offs, psum, pmax, h, (L == 0) ? 1 : 0);
        k_B<<<NG, 512, 0, stream>>>(
            psum, pmax, offs,
            W_out + (size_t)j*HINC*DD + (size_t)96*DD, beff + j*DD, aggW);
        k_C<<<(NPTS+CH-1)/CH, 512, 0, stream>>>(
            inb, st, pgw, pgb, aggW, batch,
            Weff + (size_t)j*DD*DD, tbuf, stats + 2*L);
    }
    k_read<<<NG, 256, 0, stream>>>(tbuf, stats + 16, gln_w + 2*DD, gln_b + 2*DD,
                                   offs, Wp, bp, lnp_w, lnp_b, Wpo, bpo, out);
}